// Round 8
// baseline (83.020 us; speedup 1.0000x reference)
//
#include <hip/hip_runtime.h>

typedef _Float16 half_t;
typedef __attribute__((ext_vector_type(8))) _Float16 half8;
typedef __attribute__((ext_vector_type(4))) float f32x4;
typedef __attribute__((ext_vector_type(8))) short short8v;
typedef unsigned short u16;
typedef unsigned int u32;

// Log2-domain scaled math (round-4/6/7 verified): E' = (1-cos)*SCALE,
// u',v' are log2 of the real scaling factors.
#define SCALE_F     14.4269504f     /* 10*log2(e) */
#define INV_SCALE_F 0.0693147181f
#define C_MU       -9.99998523f     /* log2(1/1024+1e-8) */
#define C_NU       -9.99998523f
#define MU_F        0.000976572498f /* 2^C_MU */
#define ERR_STOP_B  1.44269504f     /* 0.1 * SCALE, per-batch stop */
#define MAX_ITER    100
#define SPIN_LIMIT  50000000LL

#define SMEM_E   131072             /* 64*1024 fp16 */
#define SMEM_CP  16384              /* 4*1024 f32   */
#define SMEM_V   4096               /* 1024 f32     */
#define SMEM_RED 256
#define SMEM_TOTAL (SMEM_E + SMEM_CP + SMEM_V + SMEM_RED)

#define PSTRIDE  1040               /* u32/slice: 1024 f32 cols + werr + pad */
#define PWORDS   (2*16*16*PSTRIDE)  /* parity-dbuf total = 532480 */

__device__ __forceinline__ float fexp2(float x) { return __builtin_amdgcn_exp2f(x); }
__device__ __forceinline__ float flog2(float x) { return __builtin_amdgcn_logf(x); }
__device__ __forceinline__ float frcp(float x)  { return __builtin_amdgcn_rcpf(x); }

__device__ __forceinline__ u16 f2bf(float f) {
  unsigned u = __float_as_uint(f);
  return (u16)((u + 0x7fffu + ((u >> 16) & 1u)) >> 16);
}

__device__ __forceinline__ u32 agload(const u32* p) {
  return __hip_atomic_load(p, __ATOMIC_RELAXED, __HIP_MEMORY_SCOPE_AGENT);
}
__device__ __forceinline__ void agstore(u32* p, u32 v) {
  __hip_atomic_store(p, v, __ATOMIC_RELAXED, __HIP_MEMORY_SCOPE_AGENT);
}

// ---------------- K1: normalize x,y -> bf16 rows; zero per-call state ------
__global__ __launch_bounds__(256) void mfa_prep(const float* __restrict__ x,
                                                const float* __restrict__ y,
                                                u16* __restrict__ Xn,
                                                u16* __restrict__ Yn,
                                                u32* __restrict__ partials,
                                                float* __restrict__ cost) {
  int g = blockIdx.x * 256 + threadIdx.x;    // 65536 threads
  if (g < 16) cost[g] = 0.0f;
  #pragma unroll
  for (int j = 0; j < 9; ++j) {              // zero tagged partials (tags -> 0)
    int idx = (j << 16) + g;
    if (idx < PWORDS) partials[idx] = 0u;
  }

  int wid = g >> 6;                          // 0..1023 waves
  int lane = threadIdx.x & 63;
  for (int rr = 0; rr < 32; ++rr) {
    int row = wid + (rr << 10);              // 0..32767
    const float* src = (row < 16384) ? x + (size_t)row * 256
                                     : y + (size_t)(row - 16384) * 256;
    float4 xa = ((const float4*)src)[lane];
    float ss = xa.x*xa.x + xa.y*xa.y + xa.z*xa.z + xa.w*xa.w;
    #pragma unroll
    for (int off = 32; off; off >>= 1) ss += __shfl_xor(ss, off);
    float inv = 1.0f / fmaxf(sqrtf(ss), 1e-8f);
    ushort4 o;
    o.x = f2bf(xa.x * inv); o.y = f2bf(xa.y * inv);
    o.z = f2bf(xa.z * inv); o.w = f2bf(xa.w * inv);
    u16* dst = ((row < 16384) ? Xn + ((size_t)row << 8)
                              : Yn + ((size_t)(row - 16384) << 8)) + lane * 4;
    *(ushort4*)dst = o;
  }
}

// ---------------- K2: fused MFMA E-build + LDS-resident Sinkhorn ----------
// Plain launch, 256 blocks x 512 thr, 151.8 KB LDS -> 1 block/CU.
// XCD remap heuristic: all 16 blocks of a batch on one XCD; correctness
// relies only on agent-scope tagged words (per-word self-sync, no fences).
__global__ __launch_bounds__(512, 1) void mfa_sink_fused(
    const u16* __restrict__ Xn, const u16* __restrict__ Yn,
    u32* __restrict__ partials, float* __restrict__ cost) {
  extern __shared__ char smem[];
  half_t* Els  = (half_t*)smem;                               // [64][1024] E'
  float*  cpb  = (float*)(smem + SMEM_E);                     // [4][1024]
  float*  vsh  = (float*)(smem + SMEM_E + SMEM_CP);           // [1024] v'
  float*  sred = (float*)(smem + SMEM_E + SMEM_CP + SMEM_V);  // [8] + err slot

  const int t = threadIdx.x, w = t >> 6, lane = t & 63;
  const int lane15 = lane & 15, lgrp = lane >> 4;
  const int blk = blockIdx.x;
  const int b = ((blk & 7) << 1) | ((blk >> 7) & 1);
  const int k = (blk >> 3) & 15;

  // ---- build E' (64 x 1024 fp16) in LDS via MFMA from bf16 Xn/Yn ----
  {
    const u16* Xb = Xn + ((size_t)((b << 10) + (k << 6)) << 8);  // 64 rows
    const u16* Yb = Yn + ((size_t)(b << 10) << 8);               // 1024 rows
    const int wcol = w << 7;                 // wave's 128-col slice
    #pragma unroll
    for (int pass = 0; pass < 2; ++pass) {
      const int c0 = wcol + (pass << 6);     // 64-col group
      f32x4 acc[4][4];
      #pragma unroll
      for (int i = 0; i < 4; ++i)
        #pragma unroll
        for (int j = 0; j < 4; ++j) acc[i][j] = (f32x4){0.f, 0.f, 0.f, 0.f};
      for (int ks = 0; ks < 8; ++ks) {
        const int koff = (ks << 5) + (lgrp << 3);
        short8v a[4], bb[4];
        #pragma unroll
        for (int i = 0; i < 4; ++i)
          a[i] = *(const short8v*)(Xb + (((i << 4) + lane15) << 8) + koff);
        #pragma unroll
        for (int j = 0; j < 4; ++j)
          bb[j] = *(const short8v*)(Yb + ((size_t)(c0 + (j << 4) + lane15) << 8) + koff);
        #pragma unroll
        for (int i = 0; i < 4; ++i)
          #pragma unroll
          for (int j = 0; j < 4; ++j)
            acc[i][j] = __builtin_amdgcn_mfma_f32_16x16x32_bf16(a[i], bb[j], acc[i][j], 0, 0, 0);
      }
      #pragma unroll
      for (int i = 0; i < 4; ++i)
        #pragma unroll
        for (int j = 0; j < 4; ++j) {
          const int col = c0 + (j << 4) + lane15;
          #pragma unroll
          for (int q = 0; q < 4; ++q) {
            const int row = (i << 4) + (lgrp << 2) + q;
            Els[(row << 10) + col] = (half_t)((1.0f - acc[i][j][q]) * SCALE_F);
          }
        }
    }
  }
  vsh[t] = 0.0f; vsh[t + 512] = 0.0f;
  __syncthreads();

  float ureg[8];
  #pragma unroll
  for (int r = 0; r < 8; ++r) ureg[r] = 0.0f;

  const int mlo = lane << 3;
  int it = 0;
  for (; it < MAX_ITER; ++it) {
    // ---- load v' ----
    const f32x4* v4 = (const f32x4*)vsh;
    f32x4 va4 = v4[lane*2], vb4 = v4[lane*2 + 1];
    f32x4 vc4 = v4[128 + lane*2], vd4 = v4[128 + lane*2 + 1];
    float vv[16];
    vv[0]=va4.x; vv[1]=va4.y; vv[2]=va4.z; vv[3]=va4.w;
    vv[4]=vb4.x; vv[5]=vb4.y; vv[6]=vb4.z; vv[7]=vb4.w;
    vv[8]=vc4.x; vv[9]=vc4.y; vv[10]=vc4.z; vv[11]=vc4.w;
    vv[12]=vd4.x; vv[13]=vd4.y; vv[14]=vd4.z; vv[15]=vd4.w;

    float colacc[16];
    #pragma unroll
    for (int j = 0; j < 16; ++j) colacc[j] = 0.0f;
    float werr = 0.0f;

    // ---- fused u-update + col-partial accumulation (E' from LDS) ----
    #pragma unroll
    for (int r = 0; r < 8; ++r) {
      const half8* E8 = (const half8*)(Els + (((w << 3) + r) << 10));
      half8 ea = E8[lane], eb = E8[lane + 64];
      float rt[16];
      float s = 0.0f;
      #pragma unroll
      for (int j = 0; j < 8; ++j) { rt[j] = fexp2(vv[j] - (float)ea[j]); s += rt[j]; }
      #pragma unroll
      for (int j = 0; j < 8; ++j) { rt[8+j] = fexp2(vv[8+j] - (float)eb[j]); s += rt[8+j]; }
      #pragma unroll
      for (int off = 32; off; off >>= 1) s += __shfl_xor(s, off);
      float unew = C_MU - flog2(s);
      float eu = MU_F * frcp(s);          // 2^u'
      werr += fabsf(unew - ureg[r]);
      ureg[r] = unew;
      #pragma unroll
      for (int j = 0; j < 16; ++j) colacc[j] += rt[j] * eu;
    }
    if (lane == 0) sred[w] = werr;

    // ---- 8-wave col reduce via cpb[4][1024] ----
    if (w < 4) {
      #pragma unroll
      for (int j = 0; j < 4; ++j) {
        *(f32x4*)&cpb[w*1024 + mlo + 4*j - ((j>=2)?8:0) + ((j>=2)?512:0)] =
            (f32x4){colacc[4*j], colacc[4*j+1], colacc[4*j+2], colacc[4*j+3]};
      }
    }
    __syncthreads();
    if (w >= 4) {
      const int wb = (w - 4) * 1024;
      #pragma unroll
      for (int j = 0; j < 8; ++j) cpb[wb + mlo + j] += colacc[j];
      #pragma unroll
      for (int j = 0; j < 8; ++j) cpb[wb + 512 + mlo + j] += colacc[8 + j];
    }
    __syncthreads();

    // ---- publish f32 col-partials + werr, low-2-bit iteration tag ------
    const int p = it & 1;
    const u32 tag = (u32)((it + 1) & 3);     // never 0 => poison/zero-safe
    {
      u32* ps = partials + (size_t)((((p << 4) | b) << 4) | k) * PSTRIDE;
      float2 q0 = *(const float2*)&cpb[2*t];
      float2 q1 = *(const float2*)&cpb[1024 + 2*t];
      float2 q2 = *(const float2*)&cpb[2048 + 2*t];
      float2 q3 = *(const float2*)&cpb[3072 + 2*t];
      float ca = q0.x + q1.x + q2.x + q3.x;
      float cb = q0.y + q1.y + q2.y + q3.y;
      agstore(&ps[2*t],     (__float_as_uint(ca) & ~3u) | tag);
      agstore(&ps[2*t + 1], (__float_as_uint(cb) & ~3u) | tag);
      if (t == 0) {
        float be = sred[0]+sred[1]+sred[2]+sred[3]+sred[4]+sred[5]+sred[6]+sred[7];
        agstore(&ps[1024], (__float_as_uint(be) & ~3u) | tag);
      }
    }
    // no drain barrier, no flag, no poll: readers self-sync on per-word tags

    // ---- read all 16 slices (tag-spin), v' recompute + werr gather -----
    {
      const u32* pb32 = partials + (size_t)(((p << 4) | b) << 4) * PSTRIDE;
      u32 wa[16], wb[16];
      #pragma unroll
      for (int j = 0; j < 16; ++j) {         // pipelined first pass
        wa[j] = agload(&pb32[j * PSTRIDE + 2*t]);
        wb[j] = agload(&pb32[j * PSTRIDE + 2*t + 1]);
      }
      long long tws = clock64();
      #pragma unroll
      for (int j = 0; j < 16; ++j) {
        while ((wa[j] & 3u) != tag) {
          wa[j] = agload(&pb32[j * PSTRIDE + 2*t]);
          if (clock64() - tws > SPIN_LIMIT) break;
        }
        while ((wb[j] & 3u) != tag) {
          wb[j] = agload(&pb32[j * PSTRIDE + 2*t + 1]);
          if (clock64() - tws > SPIN_LIMIT) break;
        }
      }
      float t0s = 0.0f, t1s = 0.0f;
      #pragma unroll
      for (int j = 0; j < 16; ++j) {
        t0s += __uint_as_float(wa[j]);
        t1s += __uint_as_float(wb[j]);
      }
      if (w == 0) {
        float we = 0.0f;
        if (lane < 16) {
          u32 ww = agload(&pb32[lane * PSTRIDE + 1024]);
          while ((ww & 3u) != tag) {
            ww = agload(&pb32[lane * PSTRIDE + 1024]);
            if (clock64() - tws > SPIN_LIMIT) break;
          }
          we = __uint_as_float(ww);
        }
        #pragma unroll
        for (int off = 8; off; off >>= 1) we += __shfl_xor(we, off);
        if (lane == 0) sred[8] = we;
      }
      vsh[2*t]     += C_NU - flog2(t0s);
      vsh[2*t + 1] += C_NU - flog2(t1s);
    }
    __syncthreads();

    if (sred[8] < ERR_STOP_B) break;   // per-batch stop, update applied (ref freeze)
  }

  // ---- cost: sum 2^(u'+v'-E') * E' / SCALE ----
  {
    const f32x4* v4 = (const f32x4*)vsh;
    f32x4 va4 = v4[lane*2], vb4 = v4[lane*2 + 1];
    f32x4 vc4 = v4[128 + lane*2], vd4 = v4[128 + lane*2 + 1];
    float vv[16];
    vv[0]=va4.x; vv[1]=va4.y; vv[2]=va4.z; vv[3]=va4.w;
    vv[4]=vb4.x; vv[5]=vb4.y; vv[6]=vb4.z; vv[7]=vb4.w;
    vv[8]=vc4.x; vv[9]=vc4.y; vv[10]=vc4.z; vv[11]=vc4.w;
    vv[12]=vd4.x; vv[13]=vd4.y; vv[14]=vd4.z; vv[15]=vd4.w;
    float cacc = 0.0f;
    #pragma unroll
    for (int r = 0; r < 8; ++r) {
      const half8* E8 = (const half8*)(Els + (((w << 3) + r) << 10));
      half8 ea = E8[lane], eb = E8[lane + 64];
      float un = ureg[r];
      #pragma unroll
      for (int j = 0; j < 8; ++j) {
        float e = (float)ea[j];
        cacc += fexp2(un + vv[j] - e) * e;
      }
      #pragma unroll
      for (int j = 0; j < 8; ++j) {
        float e = (float)eb[j];
        cacc += fexp2(un + vv[8+j] - e) * e;
      }
    }
    #pragma unroll
    for (int off = 32; off; off >>= 1) cacc += __shfl_xor(cacc, off);
    if (lane == 0) sred[w] = cacc;
    __syncthreads();
    if (t == 0)
      atomicAdd(&cost[b], (sred[0]+sred[1]+sred[2]+sred[3]+sred[4]+sred[5]+
                           sred[6]+sred[7]) * INV_SCALE_F);
  }
}

extern "C" void kernel_launch(void* const* d_in, const int* in_sizes, int n_in,
                              void* d_out, int out_size, void* d_ws, size_t ws_size,
                              hipStream_t stream) {
  const float* x = (const float*)d_in[0];
  const float* y = (const float*)d_in[1];
  float* cost = (float*)d_out;

  char* base = (char*)d_ws;
  u16* Xn       = (u16*)base;                          // 8 MB
  u16* Yn       = (u16*)(base + 8388608);              // 8 MB
  u32* partials = (u32*)(base + 16777216);             // 532480 u32 ~= 2.03 MB
  size_t needed = 16777216 + (size_t)PWORDS * 4;
  if (ws_size < needed) return;                        // ~18.8 MB needed

  mfa_prep<<<256, 256, 0, stream>>>(x, y, Xn, Yn, partials, cost);

  (void)hipFuncSetAttribute((const void*)mfa_sink_fused,
                            hipFuncAttributeMaxDynamicSharedMemorySize, SMEM_TOTAL);
  mfa_sink_fused<<<dim3(256), dim3(512), SMEM_TOTAL, stream>>>(
      Xn, Yn, partials, cost);
}